// Round 8
// baseline (478.191 us; speedup 1.0000x reference)
//
#include <hip/hip_runtime.h>
#include <math.h>

// GAT layer: N nodes, E edges, FIN=128 in-features, H=8 heads, F=16 per head.
// Round-7 pipeline (padded CSR cursors to kill L2 atomic line contention)
// — resubmitted after GPUAcquisitionTimeout (never measured):
//   memset(cnt, maxbuf)
//   k_prep     : repack Wp||Wk into MFMA B-frag bf16 layout
//   k_gemm_mfma: proj16/skip16 = bf16(x@W) via 16x16x32 MFMA; LDS-bounced
//                epilogue; fused score halves (pre-scaled log2e) + maxes.
//   k_hist     : cnt[trg*8]++            (PADDED cursors, 32B apart)
//   k_scan_*   : two-level exclusive scan (reads cnt strided, writes offs;
//                scan_add also re-seeds cnt[i*8] = offs[i] as scatter cursors)
//   k_scatter  : csr_src[cnt[trg*8]++] = src
//   k_agg_csr  : per-node wave gathers in-edges; start=offs[t], end=offs[t+1].

#define HF 128   // H*F
#define FIN 128
#define LOG2E 1.44269504f

typedef __attribute__((ext_vector_type(8))) short short8;   // 8 bf16 (4 VGPR)
typedef __attribute__((ext_vector_type(4))) float f32x4;    // MFMA acc

__device__ __forceinline__ unsigned int enc_f(float f) {
    unsigned int u = __float_as_uint(f);
    return (u & 0x80000000u) ? ~u : (u | 0x80000000u);
}
__device__ __forceinline__ float dec_f(unsigned int e) {
    return (e & 0x80000000u) ? __uint_as_float(e ^ 0x80000000u) : __uint_as_float(~e);
}
__device__ __forceinline__ unsigned short f2bf(float f) {   // RNE f32->bf16
    unsigned int u = __float_as_uint(f);
    return (unsigned short)((u + 0x7FFFu + ((u >> 16) & 1u)) >> 16);
}
__device__ __forceinline__ float bf_lo(unsigned int u) { return __uint_as_float(u << 16); }
__device__ __forceinline__ float bf_hi(unsigned int u) { return __uint_as_float(u & 0xFFFF0000u); }

// ---------------- W repack into MFMA B-frag layout ----------------
__global__ __launch_bounds__(256) void k_prep(
    const float* __restrict__ Wp, const float* __restrict__ Wk,
    unsigned short* __restrict__ Wb)
{
    const int ct = blockIdx.x;          // 0..15
    const int t = threadIdx.x;
    const int ks = t >> 6, lane = t & 63;
    const int k0 = ks * 32 + (lane >> 4) * 8;
    const int c  = ct * 16 + (lane & 15);
    const float* W = (c < 128) ? (Wp + c) : (Wk + c - 128);
    unsigned short v[8];
#pragma unroll
    for (int j = 0; j < 8; j++) v[j] = f2bf(W[(k0 + j) * HF]);
    uint4 q;
    q.x = v[0] | ((unsigned int)v[1] << 16);
    q.y = v[2] | ((unsigned int)v[3] << 16);
    q.z = v[4] | ((unsigned int)v[5] << 16);
    q.w = v[6] | ((unsigned int)v[7] << 16);
    *(uint4*)(Wb + ((size_t)(ct * 4 + ks) * 64 + lane) * 8) = q;
}

// ---------------- MFMA GEMM + LDS-bounced epilogue + fused scores ----------------
__global__ __launch_bounds__(256) void k_gemm_mfma(
    const float* __restrict__ x, const unsigned short* __restrict__ Wb,
    const float* __restrict__ av_src, const float* __restrict__ av_trg,
    unsigned short* __restrict__ proj16, unsigned short* __restrict__ skip16,
    float* __restrict__ ssrc, float* __restrict__ strg,
    unsigned int* __restrict__ maxbuf, int N)
{
    __shared__ unsigned short xs[64 * FIN];    // 16 KB, swizzled bf16 x-tile
    __shared__ unsigned short ob[64][256];     // 32 KB, swizzled bf16 out-tile
    __shared__ unsigned int smax[16];
    char* xb = (char*)xs;
    const int t = threadIdx.x;
    const int w = t >> 6, lane = t & 63;
    const int row0 = blockIdx.x * 64;
    if (t < 16) smax[t] = 0u;

    // B-frags in registers (L2-hot)
    short8 b[4][4];
    {
        const short8* wb8 = (const short8*)Wb;
#pragma unroll
        for (int nt = 0; nt < 4; nt++)
#pragma unroll
            for (int ks = 0; ks < 4; ks++)
                b[nt][ks] = wb8[(size_t)(w * 16 + nt * 4 + ks) * 64 + lane];
    }

    // stage x tile -> bf16 LDS (swizzled byte ^= (row&7)<<4)
    {
        const float4* xg = (const float4*)(x + (size_t)row0 * FIN);
#pragma unroll
        for (int it = 0; it < 8; it++) {
            const int i = t + it * 256;
            const int row = i >> 5, c4 = i & 31;
            float4 v = make_float4(0.f, 0.f, 0.f, 0.f);
            if (row0 + row < N) v = xg[i];
            ushort4 pk;
            pk.x = f2bf(v.x); pk.y = f2bf(v.y); pk.z = f2bf(v.z); pk.w = f2bf(v.w);
            const int byte = (row * 256 + c4 * 8) ^ ((row & 7) << 4);
            *(ushort4*)(xb + byte) = pk;
        }
    }
    __syncthreads();

    f32x4 acc[4][4];
#pragma unroll
    for (int mt = 0; mt < 4; mt++)
#pragma unroll
        for (int nt = 0; nt < 4; nt++)
            acc[mt][nt] = (f32x4){0.f, 0.f, 0.f, 0.f};

#pragma unroll
    for (int ks = 0; ks < 4; ks++) {
        short8 a[4];
#pragma unroll
        for (int mt = 0; mt < 4; mt++) {
            const int r = mt * 16 + (lane & 15);
            const int byte = (r * 256 + ks * 64 + (lane >> 4) * 16) ^ ((r & 7) << 4);
            a[mt] = *(const short8*)(xb + byte);
        }
#pragma unroll
        for (int mt = 0; mt < 4; mt++)
#pragma unroll
            for (int nt = 0; nt < 4; nt++)
                acc[mt][nt] = __builtin_amdgcn_mfma_f32_16x16x32_bf16(
                    a[mt], b[nt][ks], acc[mt][nt], 0, 0, 0);
    }

    // ---- D frags -> ob (bf16, swizzled). frag: col=lane&15, row=(lane>>4)*4+reg
    const int g = lane >> 4;
#pragma unroll
    for (int nt = 0; nt < 4; nt++) {
        const int csw = (w * 64 + nt * 16 + (lane & 15)) ^ (g << 4);
#pragma unroll
        for (int mt = 0; mt < 4; mt++) {
            const int rbase = mt * 16 + (g << 2);
            f32x4 v = acc[mt][nt];
#pragma unroll
            for (int reg = 0; reg < 4; reg++)
                ob[rbase + reg][csw] = f2bf(v[reg]);
        }
    }
    __syncthreads();

    // ---- coalesced 16B stores
#pragma unroll
    for (int it = 0; it < 8; it++) {
        const int i = t + it * 256;
        const int row = i >> 5, seg = i & 31;
        const int c0 = (seg * 8) ^ (((row >> 2) & 3) << 4);
        const uint4 q = *(const uint4*)&ob[row][c0];
        const int grow = row0 + row;
        if (grow < N) {
            if (seg < 16) *(uint4*)(proj16 + (size_t)grow * HF + seg * 8) = q;
            else          *(uint4*)(skip16 + (size_t)grow * HF + (seg - 16) * 8) = q;
        }
    }

    // ---- fused scores: 512 (row,head) tasks, 2 per thread; pre-scaled by log2e
#pragma unroll
    for (int j = 0; j < 2; j++) {
        const int id = (t << 1) | j;
        const int row = id >> 3, h = id & 7;
        const int cb = (h * 16) ^ (((row >> 2) & 3) << 4);
        const unsigned int* pq = (const unsigned int*)&ob[row][cb];
        float ps = 0.f, pt = 0.f;
#pragma unroll
        for (int gg = 0; gg < 8; gg++) {
            const unsigned int q = pq[gg];
            const float lo = bf_lo(q), hi = bf_hi(q);
            const float2 A = *(const float2*)(av_src + h * 16 + gg * 2);
            const float2 T = *(const float2*)(av_trg + h * 16 + gg * 2);
            ps += lo * A.x + hi * A.y;
            pt += lo * T.x + hi * T.y;
        }
        ps *= LOG2E; pt *= LOG2E;
        const int grow = row0 + row;
        if (grow < N) {
            ssrc[(size_t)grow * 8 + h] = ps;
            strg[(size_t)grow * 8 + h] = pt;
            atomicMax(&smax[h], enc_f(ps));
            atomicMax(&smax[8 + h], enc_f(pt));
        }
    }
    __syncthreads();
    if (t < 16) atomicMax(&maxbuf[t], smax[t]);
}

// ---------------- degree histogram (2 edges/thread, PADDED cursors) ----------------
__global__ __launch_bounds__(256) void k_hist(
    const int* __restrict__ ei, int* __restrict__ cnt, int E)
{
    const int e = (blockIdx.x * 256 + threadIdx.x) * 2;
    if (e + 1 < E) {
        const int2 tg = *(const int2*)(ei + E + e);
        atomicAdd(&cnt[tg.x << 3], 1);
        atomicAdd(&cnt[tg.y << 3], 1);
    } else if (e < E) {
        atomicAdd(&cnt[ei[E + e] << 3], 1);
    }
}

// ---------------- two-level exclusive scan (reads padded cnt, writes compact offs) ----------------
__global__ __launch_bounds__(1024) void k_scan_local(
    const int* __restrict__ cnt, int* __restrict__ offs,
    int* __restrict__ bsums, int N)
{
    __shared__ int lds[1024];
    const int t = threadIdx.x;
    const int base = blockIdx.x * 4096 + t * 4;
    int4 v;
    v.x = (base + 0 < N) ? cnt[(base + 0) << 3] : 0;
    v.y = (base + 1 < N) ? cnt[(base + 1) << 3] : 0;
    v.z = (base + 2 < N) ? cnt[(base + 2) << 3] : 0;
    v.w = (base + 3 < N) ? cnt[(base + 3) << 3] : 0;
    const int s = v.x + v.y + v.z + v.w;
    lds[t] = s;
    __syncthreads();
    for (int off = 1; off < 1024; off <<= 1) {
        int u = (t >= off) ? lds[t - off] : 0;
        __syncthreads();
        lds[t] += u;
        __syncthreads();
    }
    if (t == 1023) bsums[blockIdx.x] = lds[1023];
    int run = lds[t] - s;
    int4 w;
    w.x = run; run += v.x;
    w.y = run; run += v.y;
    w.z = run; run += v.z;
    w.w = run;
    if (base + 3 < N) *(int4*)(offs + base) = w;
    else {
        if (base + 0 < N) offs[base + 0] = w.x;
        if (base + 1 < N) offs[base + 1] = w.y;
        if (base + 2 < N) offs[base + 2] = w.z;
        if (base + 3 < N) offs[base + 3] = w.w;
    }
}

__global__ __launch_bounds__(256) void k_scan_bsum(int* __restrict__ bsums, int nb)
{
    __shared__ int lds[256];
    const int t = threadIdx.x;
    const int v = (t < nb) ? bsums[t] : 0;
    lds[t] = v;
    __syncthreads();
    for (int off = 1; off < 256; off <<= 1) {
        int u = (t >= off) ? lds[t - off] : 0;
        __syncthreads();
        lds[t] += u;
        __syncthreads();
    }
    if (t < nb) bsums[t] = lds[t] - v;
}

// adds block prefix AND seeds padded scatter cursors cnt[i*8] = offs[i]
__global__ __launch_bounds__(1024) void k_scan_add(
    int* __restrict__ offs, int* __restrict__ cnt,
    const int* __restrict__ bsums, int N)
{
    const int add = bsums[blockIdx.x];
    const int base = blockIdx.x * 4096 + threadIdx.x * 4;
    if (base + 3 < N) {
        int4 v = *(int4*)(offs + base);
        v.x += add; v.y += add; v.z += add; v.w += add;
        *(int4*)(offs + base) = v;
        cnt[(base + 0) << 3] = v.x;
        cnt[(base + 1) << 3] = v.y;
        cnt[(base + 2) << 3] = v.z;
        cnt[(base + 3) << 3] = v.w;
    } else {
        for (int i = 0; i < 4; i++) if (base + i < N) {
            const int v = offs[base + i] + add;
            offs[base + i] = v;
            cnt[(base + i) << 3] = v;
        }
    }
}

// ---------------- scatter edge srcs into CSR (padded cursors) ----------------
__global__ __launch_bounds__(256) void k_scatter(
    const int* __restrict__ ei, int* __restrict__ cnt,
    int* __restrict__ csr_src, int E)
{
    const int e = (blockIdx.x * 256 + threadIdx.x) * 2;
    if (e + 1 < E) {
        const int2 s  = *(const int2*)(ei + e);
        const int2 tg = *(const int2*)(ei + E + e);
        const int p0 = atomicAdd(&cnt[tg.x << 3], 1);
        csr_src[p0] = s.x;
        const int p1 = atomicAdd(&cnt[tg.y << 3], 1);
        csr_src[p1] = s.y;
    } else if (e < E) {
        const int pos = atomicAdd(&cnt[ei[E + e] << 3], 1);
        csr_src[pos] = ei[e];
    }
}

// ---------------- gather aggregation: one 64-lane wave per target node ----------------
__global__ __launch_bounds__(256) void k_agg_csr(
    const int* __restrict__ offs, const int* __restrict__ csr_src,
    const float* __restrict__ ssrc, const float* __restrict__ strg,
    const unsigned short* __restrict__ proj16, const unsigned short* __restrict__ skip16,
    const float* __restrict__ bias, const unsigned int* __restrict__ maxbuf,
    float* __restrict__ out, int N, int E)
{
    __shared__ float Msh;
    if (threadIdx.x == 0) {
        float M = -3e38f;
        for (int h = 0; h < 8; h++) M = fmaxf(M, dec_f(maxbuf[h]) + dec_f(maxbuf[8 + h]));
        Msh = M;
    }
    __syncthreads();
    const float M = Msh;
    const int wid = threadIdx.x >> 6;
    const int l   = threadIdx.x & 63;
    const int t   = blockIdx.x * 4 + wid;
    if (t >= N) return;
    const int h = l >> 3;

    const int start = offs[t];
    const int end   = (t + 1 < N) ? offs[t + 1] : E;
    const int n     = end - start;
    const float st  = strg[(unsigned)t * 8u + h];
    const unsigned int* pu = (const unsigned int*)proj16;

    float acc0 = 0.f, acc1 = 0.f, den = 0.f;
    int s1 = 0; unsigned pv0 = 0; float ss0 = 0.f;
    if (n > 0) {
        const int s0 = csr_src[start];
        s1  = (n > 1) ? csr_src[start + 1] : s0;
        pv0 = pu[(unsigned)s0 * 64u + l];
        ss0 = ssrc[(unsigned)s0 * 8u + h];
    }
    for (int i = start; i < end; ++i) {
        const int s2 = (i + 2 < end) ? csr_src[i + 2] : s1;
        const unsigned pv1 = pu[(unsigned)s1 * 64u + l];
        const float ss1 = ssrc[(unsigned)s1 * 8u + h];
        float z = ss0 + st;
        z = fmaxf(z, 0.2f * z);                       // lrelu (commutes with +scale)
        const float p = __builtin_amdgcn_exp2f(z - M);
        den += p;
        acc0 = fmaf(p, bf_lo(pv0), acc0);
        acc1 = fmaf(p, bf_hi(pv0), acc1);
        pv0 = pv1; ss0 = ss1; s1 = s2;
    }

    const float inv = 1.f / (den + 1e-16f);
    const unsigned skv = ((const unsigned int*)skip16)[(unsigned)t * 64u + l];
    const float2 bv = *(const float2*)(bias + (l << 1));
    float r0 = fmaf(acc0, inv, bf_lo(skv) + bv.x);
    float r1 = fmaf(acc1, inv, bf_hi(skv) + bv.y);
    r0 = r0 > 0.f ? r0 : expm1f(r0);
    r1 = r1 > 0.f ? r1 : expm1f(r1);
    *(float2*)(out + (size_t)t * HF + (l << 1)) = make_float2(r0, r1);
}

extern "C" void kernel_launch(void* const* d_in, const int* in_sizes, int n_in,
                              void* d_out, int out_size, void* d_ws, size_t ws_size,
                              hipStream_t stream)
{
    const float* x      = (const float*)d_in[0];
    const int*   ei     = (const int*)d_in[1];
    const float* W_proj = (const float*)d_in[2];
    const float* a_src  = (const float*)d_in[3];
    const float* a_trg  = (const float*)d_in[4];
    const float* W_skip = (const float*)d_in[5];
    const float* bias   = (const float*)d_in[6];
    float* out = (float*)d_out;

    const int N = in_sizes[0] / FIN;
    const int E = in_sizes[1] / 2;

    unsigned short* proj16 = (unsigned short*)d_ws;               // N*128 bf16
    unsigned short* skip16 = proj16 + (size_t)N * HF;             // N*128 bf16
    float* ssrc = (float*)(skip16 + (size_t)N * HF);              // N*8 f32
    float* strg = ssrc + (size_t)N * 8;                           // N*8 f32
    int*   offs = (int*)(strg + (size_t)N * 8);                   // N+1 ints
    unsigned int* maxbuf = (unsigned int*)(offs + (size_t)N + 1); // 16 u32
    int*   bsums = (int*)(maxbuf + 16);                           // 256 ints
    unsigned short* Wb = (unsigned short*)(((uintptr_t)(bsums + 256) + 63) & ~(uintptr_t)63); // 32768 bf16
    int*   cnt = (int*)(Wb + 32768);                              // N*8 ints, padded cursors
    int*   csr_src = cnt + (size_t)N * 8;                         // E ints

    // zero padded cursors + maxbuf (ws is poisoned 0xAA before every launch)
    hipMemsetAsync(cnt, 0, (size_t)N * 8 * sizeof(int), stream);
    hipMemsetAsync(maxbuf, 0, 16 * sizeof(unsigned int), stream);

    k_prep<<<16, 256, 0, stream>>>(W_proj, W_skip, Wb);
    k_gemm_mfma<<<(N + 63) / 64, 256, 0, stream>>>(x, Wb, a_src, a_trg,
                                                   proj16, skip16, ssrc, strg, maxbuf, N);
    k_hist<<<(E / 2 + 255) / 256, 256, 0, stream>>>(ei, cnt, E);

    const int scan_blocks = (N + 4095) / 4096;
    k_scan_local<<<scan_blocks, 1024, 0, stream>>>(cnt, offs, bsums, N);
    k_scan_bsum<<<1, 256, 0, stream>>>(bsums, scan_blocks);
    k_scan_add<<<scan_blocks, 1024, 0, stream>>>(offs, cnt, bsums, N);

    k_scatter<<<(E / 2 + 255) / 256, 256, 0, stream>>>(ei, cnt, csr_src, E);
    k_agg_csr<<<(N + 3) / 4, 256, 0, stream>>>(offs, csr_src, ssrc, strg,
                                               proj16, skip16, bias, maxbuf, out, N, E);
}